// Round 8
// baseline (260.320 us; speedup 1.0000x reference)
//
#include <hip/hip_runtime.h>
#include <hip/hip_bf16.h>
#include <stdint.h>

// ---------------------------------------------------------------------------
// Causal MHA, B=2 T=4096 D=768 H=12 dk=64, bf16 MFMA path.
// R14: R13 post-mortem - flash VALUBusy 58% with ~400cyc/wave-tile of
// address recompute (compiler does not strength-reduce glds global addrs
// across barriers; m97 asm: 21 lshl_add_u64/iter). Replace per-tile address
// recompute with running per-thread pointers (+const per tile) in flash and
// both GEMMs. Flash structure = R7 + T5 setprio (89.2us measured); GEMM XCD
// remap kept (null but harmless).
// ---------------------------------------------------------------------------

typedef __attribute__((ext_vector_type(8))) short bf16x8;   // 8 bf16 = 4 VGPRs
typedef __attribute__((ext_vector_type(4))) short bf16x4;   // 4 bf16 = 2 VGPRs
typedef __attribute__((ext_vector_type(4))) float f32x4;

#define TT 4096
#define NH 12
#define DK 64
#define DMODEL 768
#define NQKV 2304

__device__ __forceinline__ unsigned short f2bf(float f) {
    union { float f; unsigned u; } v; v.f = f;
    unsigned u = v.u;
    return (unsigned short)((u + 0x7fffu + ((u >> 16) & 1u)) >> 16);  // RNE
}
__device__ __forceinline__ unsigned fbits(float f) {
    union { float f; unsigned u; } v; v.f = f; return v.u;
}
// pack two fp32 -> two bf16 (round-half-up): lo16=a, hi16=b
__device__ __forceinline__ unsigned pack_bf2(float a, float b) {
    return __builtin_amdgcn_perm(fbits(b) + 0x8000u, fbits(a) + 0x8000u, 0x07060302u);
}
// async global->LDS, 16B/lane; LDS dest = wave-uniform base + lane*16
__device__ __forceinline__ void glds16(const void* g, void* l) {
    __builtin_amdgcn_global_load_lds(
        (const __attribute__((address_space(1))) void*)g,
        (__attribute__((address_space(3))) void*)l, 16, 0, 0);
}

// ---------------------------------------------------------------------------
// prep: x->bf16 (blocks [0,6144)), W_qkv transpose ([6144,6576)),
// W_out transpose ([6576,6720)).
// ---------------------------------------------------------------------------
__global__ __launch_bounds__(256)
void prep(const float* __restrict__ x, unsigned short* __restrict__ xb,
          const float* __restrict__ Wq, unsigned short* __restrict__ Wqt,
          const float* __restrict__ Wo, unsigned short* __restrict__ Wot) {
    int b = blockIdx.x;
    if (b < 6144) {
        int i = (b * 256 + threadIdx.x) * 4;
        float4 v = *(const float4*)(x + i);
        uint2 u;
        u.x = pack_bf2(v.x, v.y);
        u.y = pack_bf2(v.z, v.w);
        *(uint2*)(xb + i) = u;
        return;
    }
    __shared__ unsigned short tile[64][65];
    const float* W; unsigned short* Wt; int K, N, bx, by;
    if (b < 6144 + 432) {
        int bb = b - 6144; bx = bb % 36; by = bb / 36;
        W = Wq; Wt = Wqt; K = DMODEL; N = NQKV;
    } else {
        int bb = b - 6576; bx = bb % 12; by = bb / 12;
        W = Wo; Wt = Wot; K = DMODEL; N = DMODEL;
    }
    int k0 = by * 64, n0 = bx * 64;
    int c = threadIdx.x & 63;
    int r0 = threadIdx.x >> 6;
    for (int p = 0; p < 16; ++p) {
        int r = r0 + p * 4;
        tile[r][c] = f2bf(W[(size_t)(k0 + r) * N + n0 + c]);
    }
    __syncthreads();
    for (int p = 0; p < 16; ++p) {
        int n = r0 + p * 4;
        Wt[(size_t)(n0 + n) * K + k0 + c] = tile[c][n];
    }
}

// ---------------------------------------------------------------------------
// QKV GEMM computing C^T: tile rows = qkv-cols (A = Wqkv_t), cols = tokens
// (B = x_bf). Q (incl. bias) pre-scaled by log2(e)/8.
// launch_bounds(256,3): 3 blocks/CU. XCD-rectangle remap; staging pointers
// strength-reduced (advance +64 els per k-step instead of recompute).
// ---------------------------------------------------------------------------
__global__ __launch_bounds__(256, 3)
void gemm_qkv(const unsigned short* __restrict__ Amat, const unsigned short* __restrict__ Bmat,
              const float* __restrict__ bias, unsigned short* __restrict__ qb,
              unsigned short* __restrict__ kb, unsigned short* __restrict__ vtb) {
    __shared__ unsigned short As[128 * 64];
    __shared__ unsigned short Bs[128 * 64];
    const int K = DMODEL;
    // XCD-rectangle remap (grid 64 x 18 = 1152 blocks, 1152 % 8 == 0)
    int bid = (int)blockIdx.y * 64 + (int)blockIdx.x;
    int idx = bid >> 3;
    int n0 = ((bid & 7) * 8 + (idx & 7)) * 128;         // token tile
    int m0 = (idx >> 3) * 128;                          // qkv-col tile
    int tid = threadIdx.x, lane = tid & 63, w = tid >> 6;
    int wm = (w >> 1) * 64, wn = (w & 1) * 64;
    int quad = lane >> 4, lc = lane & 15;

    const unsigned short* agp[4]; const unsigned short* bgp[4];
    unsigned short* alp[4]; unsigned short* blp[4];
    for (int p = 0; p < 4; ++p) {
        int c = (w * 4 + p) * 64 + lane;      // 16B chunk id in tile
        int row = c >> 3, pc = c & 7;
        int gc = pc ^ (row & 7);              // swizzle inverse
        agp[p] = Amat + (size_t)(m0 + row) * K + gc * 8;
        bgp[p] = Bmat + (size_t)(n0 + row) * K + gc * 8;
        alp[p] = &As[(w * 4 + p) * 512];
        blp[p] = &Bs[(w * 4 + p) * 512];
    }
    int foff[4][2];
    for (int mt = 0; mt < 4; ++mt)
        for (int h = 0; h < 2; ++h)
            foff[mt][h] = (mt * 16 + lc) * 64 + (((quad + 4 * h) ^ (lc & 7)) * 8);

    f32x4 acc[4][4];
    for (int a = 0; a < 4; ++a)
        for (int b2 = 0; b2 < 4; ++b2) acc[a][b2] = (f32x4){0.f, 0.f, 0.f, 0.f};

    for (int k0 = 0; k0 < K; k0 += 64) {
        for (int p = 0; p < 4; ++p) {
            glds16(agp[p], alp[p]);
            glds16(bgp[p], blp[p]);
            agp[p] += 64; bgp[p] += 64;       // running pointers, +128B
        }
        __syncthreads();
        bf16x8 af[4][2], bfr[4][2];
        for (int mt = 0; mt < 4; ++mt)
            for (int h = 0; h < 2; ++h) {
                af[mt][h]  = *(const bf16x8*)(&As[wm * 64 + foff[mt][h]]);
                bfr[mt][h] = *(const bf16x8*)(&Bs[wn * 64 + foff[mt][h]]);
            }
        for (int mt = 0; mt < 4; ++mt)
            for (int nt = 0; nt < 4; ++nt) {
                acc[mt][nt] = __builtin_amdgcn_mfma_f32_16x16x32_bf16(
                    af[mt][0], bfr[nt][0], acc[mt][nt], 0, 0, 0);
                acc[mt][nt] = __builtin_amdgcn_mfma_f32_16x16x32_bf16(
                    af[mt][1], bfr[nt][1], acc[mt][nt], 0, 0, 0);
            }
        __syncthreads();
    }
    const float c2q = 0.18033688f;            // log2(e)/8 folded into Q
    for (int mt = 0; mt < 4; ++mt) {
        int colv = m0 + wm + mt * 16 + quad * 4;      // 4 consecutive qkv-cols
        float4 bv = *(const float4*)(bias + colv);
        int h = colv / 192;
        int r = colv - h * 192;
        int which = r >> 6;                            // uniform over i (64-aligned)
        int d0 = r & 63;
        for (int nt = 0; nt < 4; ++nt) {
            int tok = n0 + wn + nt * 16 + lc;
            int b = tok >> 12, t = tok & 4095;
            size_t bh = (size_t)(b * NH + h);
            float v0 = acc[mt][nt][0] + bv.x, v1 = acc[mt][nt][1] + bv.y;
            float v2 = acc[mt][nt][2] + bv.z, v3 = acc[mt][nt][3] + bv.w;
            if (which == 0) {
                uint2 u;
                u.x = pack_bf2(v0 * c2q, v1 * c2q);
                u.y = pack_bf2(v2 * c2q, v3 * c2q);
                *(uint2*)(qb + (bh * TT + t) * DK + d0) = u;
            } else if (which == 1) {
                uint2 u;
                u.x = pack_bf2(v0, v1);
                u.y = pack_bf2(v2, v3);
                *(uint2*)(kb + (bh * TT + t) * DK + d0) = u;
            } else {
                unsigned short* vp = vtb + (bh * DK + d0) * TT + t;
                vp[0] = f2bf(v0); vp[TT] = f2bf(v1);
                vp[2 * TT] = f2bf(v2); vp[3 * TT] = f2bf(v3);
            }
        }
    }
}

// ---------------------------------------------------------------------------
// Flash attention tile body (R7 form). DIAG selects causal masking (wave-
// uniform branch at call site). PV interleaved per ktile. Row-sum l via
// ones x P MFMA (5th accumulator). T5: s_setprio(1) around MFMA clusters.
// ---------------------------------------------------------------------------
template <bool DIAG>
__device__ __forceinline__ void flash_tile(const unsigned short* __restrict__ Kb,
                                           const unsigned short* __restrict__ Vb,
                                           bf16x8 qf0, bf16x8 qf1,
                                           f32x4 (&o)[4], f32x4& ol,
                                           int kt, int q_lo, int quad, int lc) {
    int c0 = quad ^ (lc & 7);
    int sw = lc & 7;
    const bf16x4 ones = {(short)0x3F80, (short)0x3F80, (short)0x3F80, (short)0x3F80};
    for (int ktile = 0; ktile < 4; ++ktile) {
        bf16x8 kf0 = *(const bf16x8*)(&Kb[(ktile * 16 + lc) * 64 + c0 * 8]);
        bf16x8 kf1 = *(const bf16x8*)(&Kb[(ktile * 16 + lc) * 64 + (c0 ^ 4) * 8]);
        f32x4 s = (f32x4){0.f, 0.f, 0.f, 0.f};
        __builtin_amdgcn_s_setprio(1);
        s = __builtin_amdgcn_mfma_f32_16x16x32_bf16(kf0, qf0, s, 0, 0, 0);
        s = __builtin_amdgcn_mfma_f32_16x16x32_bf16(kf1, qf1, s, 0, 0, 0);
        __builtin_amdgcn_s_setprio(0);
        float p[4];
        if (DIAG) {
            int key0 = kt + ktile * 16 + quad * 4;
            int qcol = q_lo + lc;
            for (int i = 0; i < 4; ++i) {
                float e = __builtin_amdgcn_exp2f(s[i]);
                if (key0 + i > qcol) e = 0.f;
                p[i] = e;
            }
        } else {
            for (int i = 0; i < 4; ++i) p[i] = __builtin_amdgcn_exp2f(s[i]);
        }
        union { uint2 u; bf16x4 v; } pc;
        pc.u.x = pack_bf2(p[0], p[1]);
        pc.u.y = pack_bf2(p[2], p[3]);
        int c8 = (ktile * 2 + (quad >> 1)) ^ sw;
        int voff = c8 * 8 + (quad & 1) * 4;
        __builtin_amdgcn_s_setprio(1);
        ol = __builtin_amdgcn_mfma_f32_16x16x16bf16_1k(ones, pc.v, ol, 0, 0, 0);
        for (int dt = 0; dt < 4; ++dt) {
            bf16x4 vf = *(const bf16x4*)(&Vb[(dt * 16 + lc) * 64 + voff]);
            o[dt] = __builtin_amdgcn_mfma_f32_16x16x16bf16_1k(vf, pc.v, o[dt], 0, 0, 0);
        }
        __builtin_amdgcn_s_setprio(0);
    }
}

// ---------------------------------------------------------------------------
// Flash attention (causal), R7 form + running staging pointers. 256 thr =
// 4 waves x 16 q rows (64-row q tile); heavy-first; K/V glds double-buffer;
// P in registers; fixed-max softmax. Waves 0-1 stage K (ptr += 64*DK els per
// tile), waves 2-3 stage V (ptr += 64 els per tile) - no per-tile address
// recompute.
// ---------------------------------------------------------------------------
__global__ __launch_bounds__(256)
void flash_attn(const unsigned short* __restrict__ qbuf,
                const unsigned short* __restrict__ kbuf,
                const unsigned short* __restrict__ vtbuf,
                unsigned short* __restrict__ ctx) {
    __shared__ unsigned short Ks[2][64 * 64];      // [key][d], swizzled
    __shared__ unsigned short Vs[2][64 * 64];      // [d][key], swizzled
    int bh = blockIdx.x;
    int qblk = 63 - (int)blockIdx.y;               // heavy blocks dispatch first
    int tid = threadIdx.x, lane = tid & 63, w = tid >> 6;
    int quad = lane >> 4, lc = lane & 15;
    const size_t base = (size_t)bh * TT * DK;
    int col8 = ((lane & 7) ^ (lane >> 3)) * 8;     // glds swizzled source col
    size_t hb = (size_t)(bh / NH) * TT * DMODEL + (size_t)(bh % NH) * DK;

    int q_lo = qblk * 64 + w * 16;                 // this wave's 16 q rows
    int ntile = qblk + 1;

    // running staging pointers: waves 0-1 stage K rows, waves 2-3 stage V rows
    int rb = (w & 1) * 4;
    const unsigned short* sgp[4];
    int stepEls;
    if (w < 2) {
        const unsigned short* kb0 = kbuf + base + (size_t)(lane >> 3) * DK + col8;
        for (int r = 0; r < 4; ++r) sgp[r] = kb0 + (size_t)((rb + r) * 8) * DK;
        stepEls = 64 * DK;                         // next 64-key tile: +8192B
    } else {
        const unsigned short* vb0 = vtbuf + base + (size_t)(lane >> 3) * TT + col8;
        for (int r = 0; r < 4; ++r) sgp[r] = vb0 + (size_t)((rb + r) * 8) * TT;
        stepEls = 64;                              // next 64-key cols: +128B
    }

    bf16x8 qf0, qf1;                               // pre-scaled Q fragment
    {
        const unsigned short* qp = qbuf + base + (size_t)(q_lo + lc) * DK;
        qf0 = *(const bf16x8*)(qp + quad * 8);
        qf1 = *(const bf16x8*)(qp + 32 + quad * 8);
    }
    f32x4 o[4];
    for (int dt = 0; dt < 4; ++dt) o[dt] = (f32x4){0.f, 0.f, 0.f, 0.f};
    f32x4 ol = (f32x4){0.f, 0.f, 0.f, 0.f};       // row-sum accumulator

    {   // stage tile 0 -> buf 0
        if (w < 2)
            for (int r = 0; r < 4; ++r) {
                glds16(sgp[r], &Ks[0][(rb + r) * 512]);
                sgp[r] += stepEls;
            }
        else
            for (int r = 0; r < 4; ++r) {
                glds16(sgp[r], &Vs[0][(rb + r) * 512]);
                sgp[r] += stepEls;
            }
    }
    __syncthreads();

    for (int ti = 0; ti < ntile; ++ti) {
        int cur = ti & 1;
        if (ti + 1 < ntile) {                      // async prefetch -> alt buf
            if (w < 2)
                for (int r = 0; r < 4; ++r) {
                    glds16(sgp[r], &Ks[cur ^ 1][(rb + r) * 512]);
                    sgp[r] += stepEls;
                }
            else
                for (int r = 0; r < 4; ++r) {
                    glds16(sgp[r], &Vs[cur ^ 1][(rb + r) * 512]);
                    sgp[r] += stepEls;
                }
        }
        int kt = ti * 64;
        if (ti == ntile - 1)
            flash_tile<true>(&Ks[cur][0], &Vs[cur][0], qf0, qf1, o, ol,
                             kt, q_lo, quad, lc);
        else
            flash_tile<false>(&Ks[cur][0], &Vs[cur][0], qf0, qf1, o, ol,
                              kt, q_lo, quad, lc);
        __syncthreads();                           // cur consumed; alt staged
    }

    // epilogue: l_q already complete per lane (ones-MFMA); normalize, store
    float inv = 1.f / ol[0];
    int t = q_lo + lc;
    unsigned short* cp = ctx + hb + (size_t)t * DMODEL;
    for (int dt = 0; dt < 4; ++dt) {
        uint2 u;
        u.x = pack_bf2(o[dt][0] * inv, o[dt][1] * inv);
        u.y = pack_bf2(o[dt][2] * inv, o[dt][3] * inv);
        *(uint2*)(cp + dt * 16 + quad * 4) = u;
    }
}

// ---------------------------------------------------------------------------
// Out GEMM computing C^T, 64 out-cols x 128 tokens per block (768 blocks).
// A = Wout_t (64 rows), B = ctx (128 rows); unified LDS, glds staging with
// running pointers. launch_bounds(256,4): 4 blocks/CU. XCD-rectangle remap.
// ---------------------------------------------------------------------------
__global__ __launch_bounds__(256, 4)
void gemm_out(const unsigned short* __restrict__ Amat, const unsigned short* __restrict__ Bmat,
              const float* __restrict__ bias, float* __restrict__ out) {
    __shared__ unsigned short S[(64 + 128) * 64];   // A then B, 24 KB
    const int K = DMODEL;
    // XCD-rectangle remap (grid 64 x 12 = 768 blocks, 768 % 8 == 0)
    int bid = (int)blockIdx.y * 64 + (int)blockIdx.x;
    int idx = bid >> 3;
    int n0 = ((bid & 7) * 8 + (idx & 7)) * 128;        // token tile
    int m0 = (idx >> 3) * 64;                          // out-col tile
    int tid = threadIdx.x, lane = tid & 63, w = tid >> 6;
    int wm = (w & 1) * 32, wn = (w >> 1) * 64;
    int quad = lane >> 4, lc = lane & 15;

    const unsigned short* gp[6]; unsigned short* lp[6];
    for (int p = 0; p < 6; ++p) {
        int c = (w * 6 + p) * 64 + lane;      // 16B chunk id (A:0..511, B:512..1535)
        if (c < 512) {
            int row = c >> 3, gc = (c & 7) ^ (row & 7);
            gp[p] = Amat + (size_t)(m0 + row) * K + gc * 8;
        } else {
            int cb = c - 512;
            int row = cb >> 3, gc = (cb & 7) ^ (row & 7);
            gp[p] = Bmat + (size_t)(n0 + row) * K + gc * 8;
        }
        lp[p] = &S[(w * 6 + p) * 512];
    }
    int foffA[2][2], foffB[4][2];
    for (int mt = 0; mt < 2; ++mt)
        for (int h = 0; h < 2; ++h)
            foffA[mt][h] = (wm + mt * 16 + lc) * 64 + (((quad + 4 * h) ^ (lc & 7)) * 8);
    for (int nt = 0; nt < 4; ++nt)
        for (int h = 0; h < 2; ++h)
            foffB[nt][h] = 4096 + (wn + nt * 16 + lc) * 64 + (((quad + 4 * h) ^ (lc & 7)) * 8);

    f32x4 acc[2][4];
    for (int a = 0; a < 2; ++a)
        for (int b2 = 0; b2 < 4; ++b2) acc[a][b2] = (f32x4){0.f, 0.f, 0.f, 0.f};

    for (int k0 = 0; k0 < K; k0 += 64) {
        for (int p = 0; p < 6; ++p) {
            glds16(gp[p], lp[p]);
            gp[p] += 64;                       // running pointers, +128B
        }
        __syncthreads();
        bf16x8 af[2][2], bfr[4][2];
        for (int mt = 0; mt < 2; ++mt)
            for (int h = 0; h < 2; ++h) af[mt][h] = *(const bf16x8*)(&S[foffA[mt][h]]);
        for (int nt = 0; nt < 4; ++nt)
            for (int h = 0; h < 2; ++h) bfr[nt][h] = *(const bf16x8*)(&S[foffB[nt][h]]);
        for (int mt = 0; mt < 2; ++mt)
            for (int nt = 0; nt < 4; ++nt) {
                acc[mt][nt] = __builtin_amdgcn_mfma_f32_16x16x32_bf16(
                    af[mt][0], bfr[nt][0], acc[mt][nt], 0, 0, 0);
                acc[mt][nt] = __builtin_amdgcn_mfma_f32_16x16x32_bf16(
                    af[mt][1], bfr[nt][1], acc[mt][nt], 0, 0, 0);
            }
        __syncthreads();
    }
    for (int mt = 0; mt < 2; ++mt) {
        int colv = m0 + wm + mt * 16 + quad * 4;
        float4 bv = *(const float4*)(bias + colv);
        for (int nt = 0; nt < 4; ++nt) {
            int tok = n0 + wn + nt * 16 + lc;
            float4 ov;
            ov.x = acc[mt][nt][0] + bv.x;
            ov.y = acc[mt][nt][1] + bv.y;
            ov.z = acc[mt][nt][2] + bv.z;
            ov.w = acc[mt][nt][3] + bv.w;
            *(float4*)(out + (size_t)tok * DMODEL + colv) = ov;
        }
    }
}

// ---------------------------------------------------------------------------
extern "C" void kernel_launch(void* const* d_in, const int* in_sizes, int n_in,
                              void* d_out, int out_size, void* d_ws, size_t ws_size,
                              hipStream_t stream) {
    const float* x     = (const float*)d_in[0];
    // d_in[1] = mask (hard-coded causal; unused)
    const float* W_qkv = (const float*)d_in[2];
    const float* b_qkv = (const float*)d_in[3];
    const float* W_out = (const float*)d_in[4];
    const float* b_out = (const float*)d_in[5];
    float* out = (float*)d_out;

    unsigned short* ws = (unsigned short*)d_ws;
    unsigned short* Wqkv_t = ws;                                    // 2304*768
    unsigned short* Wout_t = Wqkv_t + (size_t)NQKV * DMODEL;        // 768*768
    unsigned short* q_buf  = Wout_t + (size_t)DMODEL * DMODEL;      // 24*4096*64
    unsigned short* k_buf  = q_buf  + (size_t)2 * NH * TT * DK;
    unsigned short* vt_buf = k_buf  + (size_t)2 * NH * TT * DK;
    unsigned short* ctx    = vt_buf + (size_t)2 * NH * TT * DK;     // 2*4096*768
    unsigned short* x_bf   = ctx;   // alias: dead before flash writes ctx

    prep<<<dim3(6720), 256, 0, stream>>>(x, x_bf, W_qkv, Wqkv_t, W_out, Wout_t);
    gemm_qkv<<<dim3((2 * TT) / 128, NQKV / 128), 256, 0, stream>>>(
        Wqkv_t, x_bf, b_qkv, q_buf, k_buf, vt_buf);
    flash_attn<<<dim3(2 * NH, TT / 64), 256, 0, stream>>>(q_buf, k_buf, vt_buf, ctx);
    gemm_out<<<dim3((2 * TT) / 128, DMODEL / 64), 256, 0, stream>>>(
        Wout_t, ctx, b_out, out);
}

// Round 9
// 254.803 us; speedup vs baseline: 1.0217x; 1.0217x over previous
//
#include <hip/hip_runtime.h>
#include <hip/hip_bf16.h>
#include <stdint.h>

// ---------------------------------------------------------------------------
// Causal MHA, B=2 T=4096 D=768 H=12 dk=64, bf16 MFMA path.
// R15: flash at dual-pipe saturation (~85us, MfmaUtil45+VALU55~100%) - kept
// as R14. gemm_qkv: 1152 blocks at 3/CU had a half-empty second round
// (~1.7-2x makespan). Now 4 blocks/CU via launch_bounds(256,4) with register
// -pressure reduction to fit 128 VGPR: single running A/B pointers (row&7 is
// p-invariant => agp[p]=agp0+p*8K exactly), foff collapsed to [2] with
// mt*1024 folded into ds_read offset immediates, af loaded per-mt.
// ---------------------------------------------------------------------------

typedef __attribute__((ext_vector_type(8))) short bf16x8;   // 8 bf16 = 4 VGPRs
typedef __attribute__((ext_vector_type(4))) short bf16x4;   // 4 bf16 = 2 VGPRs
typedef __attribute__((ext_vector_type(4))) float f32x4;

#define TT 4096
#define NH 12
#define DK 64
#define DMODEL 768
#define NQKV 2304

__device__ __forceinline__ unsigned short f2bf(float f) {
    union { float f; unsigned u; } v; v.f = f;
    unsigned u = v.u;
    return (unsigned short)((u + 0x7fffu + ((u >> 16) & 1u)) >> 16);  // RNE
}
__device__ __forceinline__ unsigned fbits(float f) {
    union { float f; unsigned u; } v; v.f = f; return v.u;
}
// pack two fp32 -> two bf16 (round-half-up): lo16=a, hi16=b
__device__ __forceinline__ unsigned pack_bf2(float a, float b) {
    return __builtin_amdgcn_perm(fbits(b) + 0x8000u, fbits(a) + 0x8000u, 0x07060302u);
}
// async global->LDS, 16B/lane; LDS dest = wave-uniform base + lane*16
__device__ __forceinline__ void glds16(const void* g, void* l) {
    __builtin_amdgcn_global_load_lds(
        (const __attribute__((address_space(1))) void*)g,
        (__attribute__((address_space(3))) void*)l, 16, 0, 0);
}

// ---------------------------------------------------------------------------
// prep: x->bf16 (blocks [0,6144)), W_qkv transpose ([6144,6576)),
// W_out transpose ([6576,6720)).
// ---------------------------------------------------------------------------
__global__ __launch_bounds__(256)
void prep(const float* __restrict__ x, unsigned short* __restrict__ xb,
          const float* __restrict__ Wq, unsigned short* __restrict__ Wqt,
          const float* __restrict__ Wo, unsigned short* __restrict__ Wot) {
    int b = blockIdx.x;
    if (b < 6144) {
        int i = (b * 256 + threadIdx.x) * 4;
        float4 v = *(const float4*)(x + i);
        uint2 u;
        u.x = pack_bf2(v.x, v.y);
        u.y = pack_bf2(v.z, v.w);
        *(uint2*)(xb + i) = u;
        return;
    }
    __shared__ unsigned short tile[64][65];
    const float* W; unsigned short* Wt; int K, N, bx, by;
    if (b < 6144 + 432) {
        int bb = b - 6144; bx = bb % 36; by = bb / 36;
        W = Wq; Wt = Wqt; K = DMODEL; N = NQKV;
    } else {
        int bb = b - 6576; bx = bb % 12; by = bb / 12;
        W = Wo; Wt = Wot; K = DMODEL; N = DMODEL;
    }
    int k0 = by * 64, n0 = bx * 64;
    int c = threadIdx.x & 63;
    int r0 = threadIdx.x >> 6;
    for (int p = 0; p < 16; ++p) {
        int r = r0 + p * 4;
        tile[r][c] = f2bf(W[(size_t)(k0 + r) * N + n0 + c]);
    }
    __syncthreads();
    for (int p = 0; p < 16; ++p) {
        int n = r0 + p * 4;
        Wt[(size_t)(n0 + n) * K + k0 + c] = tile[c][n];
    }
}

// ---------------------------------------------------------------------------
// QKV GEMM computing C^T: tile rows = qkv-cols (A = Wqkv_t), cols = tokens
// (B = x_bf). Q (incl. bias) pre-scaled by log2(e)/8.
// launch_bounds(256,4): 4 blocks/CU (tail fix: 1152 blocks -> 1.25 rounds).
// Register diet: single running A/B pointers (p-stride = 8K els, exact since
// row&7 is p-invariant), foff[2] + mt*1024 ds_read immediates, af per-mt.
// ---------------------------------------------------------------------------
__global__ __launch_bounds__(256, 4)
void gemm_qkv(const unsigned short* __restrict__ Amat, const unsigned short* __restrict__ Bmat,
              const float* __restrict__ bias, unsigned short* __restrict__ qb,
              unsigned short* __restrict__ kb, unsigned short* __restrict__ vtb) {
    __shared__ unsigned short As[128 * 64];
    __shared__ unsigned short Bs[128 * 64];
    const int K = DMODEL;
    // XCD-rectangle remap (grid 64 x 18 = 1152 blocks, 1152 % 8 == 0)
    int bid = (int)blockIdx.y * 64 + (int)blockIdx.x;
    int idx = bid >> 3;
    int n0 = ((bid & 7) * 8 + (idx & 7)) * 128;         // token tile
    int m0 = (idx >> 3) * 128;                          // qkv-col tile
    int tid = threadIdx.x, lane = tid & 63, w = tid >> 6;
    int wm = (w >> 1) * 64, wn = (w & 1) * 64;
    int quad = lane >> 4, lc = lane & 15;

    // staging: chunk c = (w*4+p)*64 + lane; row = (w*4+p)*8 + (lane>>3);
    // gc = (lane&7)^(lane>>3) is p-invariant; p-stride = 8*K els.
    int gc8 = ((lane & 7) ^ (lane >> 3)) * 8;
    int row0 = w * 32 + (lane >> 3);
    const unsigned short* agp0 = Amat + (size_t)(m0 + row0) * K + gc8;
    const unsigned short* bgp0 = Bmat + (size_t)(n0 + row0) * K + gc8;
    unsigned short* alp0 = &As[w * 4 * 512];
    unsigned short* blp0 = &Bs[w * 4 * 512];

    int foff[2];
    for (int h = 0; h < 2; ++h)
        foff[h] = lc * 64 + (((quad + 4 * h) ^ (lc & 7)) * 8);

    f32x4 acc[4][4];
    for (int a = 0; a < 4; ++a)
        for (int b2 = 0; b2 < 4; ++b2) acc[a][b2] = (f32x4){0.f, 0.f, 0.f, 0.f};

    for (int k0 = 0; k0 < K; k0 += 64) {
        {
            const unsigned short* ag = agp0;
            const unsigned short* bg = bgp0;
            for (int p = 0; p < 4; ++p) {
                glds16(ag, alp0 + p * 512);
                glds16(bg, blp0 + p * 512);
                ag += 8 * DMODEL; bg += 8 * DMODEL;
            }
            agp0 += 64; bgp0 += 64;            // running pointers, +128B
        }
        __syncthreads();
        bf16x8 bfr[4][2];
        for (int nt = 0; nt < 4; ++nt)
            for (int h = 0; h < 2; ++h)
                bfr[nt][h] = *(const bf16x8*)(&Bs[wn * 64 + nt * 1024 + foff[h]]);
        for (int mt = 0; mt < 4; ++mt) {
            bf16x8 af0 = *(const bf16x8*)(&As[wm * 64 + mt * 1024 + foff[0]]);
            bf16x8 af1 = *(const bf16x8*)(&As[wm * 64 + mt * 1024 + foff[1]]);
            for (int nt = 0; nt < 4; ++nt) {
                acc[mt][nt] = __builtin_amdgcn_mfma_f32_16x16x32_bf16(
                    af0, bfr[nt][0], acc[mt][nt], 0, 0, 0);
                acc[mt][nt] = __builtin_amdgcn_mfma_f32_16x16x32_bf16(
                    af1, bfr[nt][1], acc[mt][nt], 0, 0, 0);
            }
        }
        __syncthreads();
    }
    const float c2q = 0.18033688f;            // log2(e)/8 folded into Q
    for (int mt = 0; mt < 4; ++mt) {
        int colv = m0 + wm + mt * 16 + quad * 4;      // 4 consecutive qkv-cols
        float4 bv = *(const float4*)(bias + colv);
        int h = colv / 192;
        int r = colv - h * 192;
        int which = r >> 6;                            // uniform over i (64-aligned)
        int d0 = r & 63;
        for (int nt = 0; nt < 4; ++nt) {
            int tok = n0 + wn + nt * 16 + lc;
            int b = tok >> 12, t = tok & 4095;
            size_t bh = (size_t)(b * NH + h);
            float v0 = acc[mt][nt][0] + bv.x, v1 = acc[mt][nt][1] + bv.y;
            float v2 = acc[mt][nt][2] + bv.z, v3 = acc[mt][nt][3] + bv.w;
            if (which == 0) {
                uint2 u;
                u.x = pack_bf2(v0 * c2q, v1 * c2q);
                u.y = pack_bf2(v2 * c2q, v3 * c2q);
                *(uint2*)(qb + (bh * TT + t) * DK + d0) = u;
            } else if (which == 1) {
                uint2 u;
                u.x = pack_bf2(v0, v1);
                u.y = pack_bf2(v2, v3);
                *(uint2*)(kb + (bh * TT + t) * DK + d0) = u;
            } else {
                unsigned short* vp = vtb + (bh * DK + d0) * TT + t;
                vp[0] = f2bf(v0); vp[TT] = f2bf(v1);
                vp[2 * TT] = f2bf(v2); vp[3 * TT] = f2bf(v3);
            }
        }
    }
}

// ---------------------------------------------------------------------------
// Flash attention tile body (R7 form). DIAG selects causal masking (wave-
// uniform branch at call site). PV interleaved per ktile. Row-sum l via
// ones x P MFMA (5th accumulator). T5: s_setprio(1) around MFMA clusters.
// ---------------------------------------------------------------------------
template <bool DIAG>
__device__ __forceinline__ void flash_tile(const unsigned short* __restrict__ Kb,
                                           const unsigned short* __restrict__ Vb,
                                           bf16x8 qf0, bf16x8 qf1,
                                           f32x4 (&o)[4], f32x4& ol,
                                           int kt, int q_lo, int quad, int lc) {
    int c0 = quad ^ (lc & 7);
    int sw = lc & 7;
    const bf16x4 ones = {(short)0x3F80, (short)0x3F80, (short)0x3F80, (short)0x3F80};
    for (int ktile = 0; ktile < 4; ++ktile) {
        bf16x8 kf0 = *(const bf16x8*)(&Kb[(ktile * 16 + lc) * 64 + c0 * 8]);
        bf16x8 kf1 = *(const bf16x8*)(&Kb[(ktile * 16 + lc) * 64 + (c0 ^ 4) * 8]);
        f32x4 s = (f32x4){0.f, 0.f, 0.f, 0.f};
        __builtin_amdgcn_s_setprio(1);
        s = __builtin_amdgcn_mfma_f32_16x16x32_bf16(kf0, qf0, s, 0, 0, 0);
        s = __builtin_amdgcn_mfma_f32_16x16x32_bf16(kf1, qf1, s, 0, 0, 0);
        __builtin_amdgcn_s_setprio(0);
        float p[4];
        if (DIAG) {
            int key0 = kt + ktile * 16 + quad * 4;
            int qcol = q_lo + lc;
            for (int i = 0; i < 4; ++i) {
                float e = __builtin_amdgcn_exp2f(s[i]);
                if (key0 + i > qcol) e = 0.f;
                p[i] = e;
            }
        } else {
            for (int i = 0; i < 4; ++i) p[i] = __builtin_amdgcn_exp2f(s[i]);
        }
        union { uint2 u; bf16x4 v; } pc;
        pc.u.x = pack_bf2(p[0], p[1]);
        pc.u.y = pack_bf2(p[2], p[3]);
        int c8 = (ktile * 2 + (quad >> 1)) ^ sw;
        int voff = c8 * 8 + (quad & 1) * 4;
        __builtin_amdgcn_s_setprio(1);
        ol = __builtin_amdgcn_mfma_f32_16x16x16bf16_1k(ones, pc.v, ol, 0, 0, 0);
        for (int dt = 0; dt < 4; ++dt) {
            bf16x4 vf = *(const bf16x4*)(&Vb[(dt * 16 + lc) * 64 + voff]);
            o[dt] = __builtin_amdgcn_mfma_f32_16x16x16bf16_1k(vf, pc.v, o[dt], 0, 0, 0);
        }
        __builtin_amdgcn_s_setprio(0);
    }
}

// ---------------------------------------------------------------------------
// Flash attention (causal), R7 form + running staging pointers. 256 thr =
// 4 waves x 16 q rows (64-row q tile); heavy-first; K/V glds double-buffer;
// P in registers; fixed-max softmax. Waves 0-1 stage K (ptr += 64*DK els per
// tile), waves 2-3 stage V (ptr += 64 els per tile) - no per-tile address
// recompute.
// ---------------------------------------------------------------------------
__global__ __launch_bounds__(256)
void flash_attn(const unsigned short* __restrict__ qbuf,
                const unsigned short* __restrict__ kbuf,
                const unsigned short* __restrict__ vtbuf,
                unsigned short* __restrict__ ctx) {
    __shared__ unsigned short Ks[2][64 * 64];      // [key][d], swizzled
    __shared__ unsigned short Vs[2][64 * 64];      // [d][key], swizzled
    int bh = blockIdx.x;
    int qblk = 63 - (int)blockIdx.y;               // heavy blocks dispatch first
    int tid = threadIdx.x, lane = tid & 63, w = tid >> 6;
    int quad = lane >> 4, lc = lane & 15;
    const size_t base = (size_t)bh * TT * DK;
    int col8 = ((lane & 7) ^ (lane >> 3)) * 8;     // glds swizzled source col
    size_t hb = (size_t)(bh / NH) * TT * DMODEL + (size_t)(bh % NH) * DK;

    int q_lo = qblk * 64 + w * 16;                 // this wave's 16 q rows
    int ntile = qblk + 1;

    // running staging pointers: waves 0-1 stage K rows, waves 2-3 stage V rows
    int rb = (w & 1) * 4;
    const unsigned short* sgp[4];
    int stepEls;
    if (w < 2) {
        const unsigned short* kb0 = kbuf + base + (size_t)(lane >> 3) * DK + col8;
        for (int r = 0; r < 4; ++r) sgp[r] = kb0 + (size_t)((rb + r) * 8) * DK;
        stepEls = 64 * DK;                         // next 64-key tile: +8192B
    } else {
        const unsigned short* vb0 = vtbuf + base + (size_t)(lane >> 3) * TT + col8;
        for (int r = 0; r < 4; ++r) sgp[r] = vb0 + (size_t)((rb + r) * 8) * TT;
        stepEls = 64;                              // next 64-key cols: +128B
    }

    bf16x8 qf0, qf1;                               // pre-scaled Q fragment
    {
        const unsigned short* qp = qbuf + base + (size_t)(q_lo + lc) * DK;
        qf0 = *(const bf16x8*)(qp + quad * 8);
        qf1 = *(const bf16x8*)(qp + 32 + quad * 8);
    }
    f32x4 o[4];
    for (int dt = 0; dt < 4; ++dt) o[dt] = (f32x4){0.f, 0.f, 0.f, 0.f};
    f32x4 ol = (f32x4){0.f, 0.f, 0.f, 0.f};       // row-sum accumulator

    {   // stage tile 0 -> buf 0
        if (w < 2)
            for (int r = 0; r < 4; ++r) {
                glds16(sgp[r], &Ks[0][(rb + r) * 512]);
                sgp[r] += stepEls;
            }
        else
            for (int r = 0; r < 4; ++r) {
                glds16(sgp[r], &Vs[0][(rb + r) * 512]);
                sgp[r] += stepEls;
            }
    }
    __syncthreads();

    for (int ti = 0; ti < ntile; ++ti) {
        int cur = ti & 1;
        if (ti + 1 < ntile) {                      // async prefetch -> alt buf
            if (w < 2)
                for (int r = 0; r < 4; ++r) {
                    glds16(sgp[r], &Ks[cur ^ 1][(rb + r) * 512]);
                    sgp[r] += stepEls;
                }
            else
                for (int r = 0; r < 4; ++r) {
                    glds16(sgp[r], &Vs[cur ^ 1][(rb + r) * 512]);
                    sgp[r] += stepEls;
                }
        }
        int kt = ti * 64;
        if (ti == ntile - 1)
            flash_tile<true>(&Ks[cur][0], &Vs[cur][0], qf0, qf1, o, ol,
                             kt, q_lo, quad, lc);
        else
            flash_tile<false>(&Ks[cur][0], &Vs[cur][0], qf0, qf1, o, ol,
                              kt, q_lo, quad, lc);
        __syncthreads();                           // cur consumed; alt staged
    }

    // epilogue: l_q already complete per lane (ones-MFMA); normalize, store
    float inv = 1.f / ol[0];
    int t = q_lo + lc;
    unsigned short* cp = ctx + hb + (size_t)t * DMODEL;
    for (int dt = 0; dt < 4; ++dt) {
        uint2 u;
        u.x = pack_bf2(o[dt][0] * inv, o[dt][1] * inv);
        u.y = pack_bf2(o[dt][2] * inv, o[dt][3] * inv);
        *(uint2*)(cp + dt * 16 + quad * 4) = u;
    }
}

// ---------------------------------------------------------------------------
// Out GEMM computing C^T, 64 out-cols x 128 tokens per block (768 blocks).
// A = Wout_t (64 rows), B = ctx (128 rows); unified LDS, glds staging with
// running pointers. launch_bounds(256,4): 4 blocks/CU. XCD-rectangle remap.
// ---------------------------------------------------------------------------
__global__ __launch_bounds__(256, 4)
void gemm_out(const unsigned short* __restrict__ Amat, const unsigned short* __restrict__ Bmat,
              const float* __restrict__ bias, float* __restrict__ out) {
    __shared__ unsigned short S[(64 + 128) * 64];   // A then B, 24 KB
    const int K = DMODEL;
    // XCD-rectangle remap (grid 64 x 12 = 768 blocks, 768 % 8 == 0)
    int bid = (int)blockIdx.y * 64 + (int)blockIdx.x;
    int idx = bid >> 3;
    int n0 = ((bid & 7) * 8 + (idx & 7)) * 128;        // token tile
    int m0 = (idx >> 3) * 64;                          // out-col tile
    int tid = threadIdx.x, lane = tid & 63, w = tid >> 6;
    int wm = (w & 1) * 32, wn = (w >> 1) * 64;
    int quad = lane >> 4, lc = lane & 15;

    const unsigned short* gp[6]; unsigned short* lp[6];
    for (int p = 0; p < 6; ++p) {
        int c = (w * 6 + p) * 64 + lane;      // 16B chunk id (A:0..511, B:512..1535)
        if (c < 512) {
            int row = c >> 3, gc = (c & 7) ^ (row & 7);
            gp[p] = Amat + (size_t)(m0 + row) * K + gc * 8;
        } else {
            int cb = c - 512;
            int row = cb >> 3, gc = (cb & 7) ^ (row & 7);
            gp[p] = Bmat + (size_t)(n0 + row) * K + gc * 8;
        }
        lp[p] = &S[(w * 6 + p) * 512];
    }
    int foffA[2][2], foffB[4][2];
    for (int mt = 0; mt < 2; ++mt)
        for (int h = 0; h < 2; ++h)
            foffA[mt][h] = (wm + mt * 16 + lc) * 64 + (((quad + 4 * h) ^ (lc & 7)) * 8);
    for (int nt = 0; nt < 4; ++nt)
        for (int h = 0; h < 2; ++h)
            foffB[nt][h] = 4096 + (wn + nt * 16 + lc) * 64 + (((quad + 4 * h) ^ (lc & 7)) * 8);

    f32x4 acc[2][4];
    for (int a = 0; a < 2; ++a)
        for (int b2 = 0; b2 < 4; ++b2) acc[a][b2] = (f32x4){0.f, 0.f, 0.f, 0.f};

    for (int k0 = 0; k0 < K; k0 += 64) {
        for (int p = 0; p < 6; ++p) {
            glds16(gp[p], lp[p]);
            gp[p] += 64;                       // running pointers, +128B
        }
        __syncthreads();
        bf16x8 af[2][2], bfr[4][2];
        for (int mt = 0; mt < 2; ++mt)
            for (int h = 0; h < 2; ++h) af[mt][h] = *(const bf16x8*)(&S[foffA[mt][h]]);
        for (int nt = 0; nt < 4; ++nt)
            for (int h = 0; h < 2; ++h) bfr[nt][h] = *(const bf16x8*)(&S[foffB[nt][h]]);
        for (int mt = 0; mt < 2; ++mt)
            for (int nt = 0; nt < 4; ++nt) {
                acc[mt][nt] = __builtin_amdgcn_mfma_f32_16x16x32_bf16(
                    af[mt][0], bfr[nt][0], acc[mt][nt], 0, 0, 0);
                acc[mt][nt] = __builtin_amdgcn_mfma_f32_16x16x32_bf16(
                    af[mt][1], bfr[nt][1], acc[mt][nt], 0, 0, 0);
            }
        __syncthreads();
    }
    for (int mt = 0; mt < 2; ++mt) {
        int colv = m0 + wm + mt * 16 + quad * 4;
        float4 bv = *(const float4*)(bias + colv);
        for (int nt = 0; nt < 4; ++nt) {
            int tok = n0 + wn + nt * 16 + lc;
            float4 ov;
            ov.x = acc[mt][nt][0] + bv.x;
            ov.y = acc[mt][nt][1] + bv.y;
            ov.z = acc[mt][nt][2] + bv.z;
            ov.w = acc[mt][nt][3] + bv.w;
            *(float4*)(out + (size_t)tok * DMODEL + colv) = ov;
        }
    }
}

// ---------------------------------------------------------------------------
extern "C" void kernel_launch(void* const* d_in, const int* in_sizes, int n_in,
                              void* d_out, int out_size, void* d_ws, size_t ws_size,
                              hipStream_t stream) {
    const float* x     = (const float*)d_in[0];
    // d_in[1] = mask (hard-coded causal; unused)
    const float* W_qkv = (const float*)d_in[2];
    const float* b_qkv = (const float*)d_in[3];
    const float* W_out = (const float*)d_in[4];
    const float* b_out = (const float*)d_in[5];
    float* out = (float*)d_out;

    unsigned short* ws = (unsigned short*)d_ws;
    unsigned short* Wqkv_t = ws;                                    // 2304*768
    unsigned short* Wout_t = Wqkv_t + (size_t)NQKV * DMODEL;        // 768*768
    unsigned short* q_buf  = Wout_t + (size_t)DMODEL * DMODEL;      // 24*4096*64
    unsigned short* k_buf  = q_buf  + (size_t)2 * NH * TT * DK;
    unsigned short* vt_buf = k_buf  + (size_t)2 * NH * TT * DK;
    unsigned short* ctx    = vt_buf + (size_t)2 * NH * TT * DK;     // 2*4096*768
    unsigned short* x_bf   = ctx;   // alias: dead before flash writes ctx

    prep<<<dim3(6720), 256, 0, stream>>>(x, x_bf, W_qkv, Wqkv_t, W_out, Wout_t);
    gemm_qkv<<<dim3((2 * TT) / 128, NQKV / 128), 256, 0, stream>>>(
        Wqkv_t, x_bf, b_qkv, q_buf, k_buf, vt_buf);
    flash_attn<<<dim3(2 * NH, TT / 64), 256, 0, stream>>>(q_buf, k_buf, vt_buf, ctx);
    gemm_out<<<dim3((2 * TT) / 128, DMODEL / 64), 256, 0, stream>>>(
        Wout_t, ctx, b_out, out);
}

// Round 10
// 250.049 us; speedup vs baseline: 1.0411x; 1.0190x over previous
//
#include <hip/hip_runtime.h>
#include <hip/hip_bf16.h>
#include <stdint.h>

// ---------------------------------------------------------------------------
// Causal MHA, B=2 T=4096 D=768 H=12 dk=64, bf16 MFMA path.
// R16: (1) gemm_qkv retiled 192x128, 768 blocks = exactly 3/CU single round
// (was 1152@4/CU -> 4.5/CU avg, 5 worst -> 11% imbalance); staging B/output
// 24->20. (2) v_cvt_pk_bf16_f32 (1 inst) replaces add/add/perm pack (3 inst)
// in flash + gemm_qkv epilogues - flash is VALU-issue-saturated (55%), -16
// insts/wave-tile. flash otherwise R14/R15 form (87us, dual-pipe saturated).
// ---------------------------------------------------------------------------

typedef __attribute__((ext_vector_type(8))) short bf16x8;   // 8 bf16 = 4 VGPRs
typedef __attribute__((ext_vector_type(4))) short bf16x4;   // 4 bf16 = 2 VGPRs
typedef __attribute__((ext_vector_type(4))) float f32x4;

#define TT 4096
#define NH 12
#define DK 64
#define DMODEL 768
#define NQKV 2304

__device__ __forceinline__ unsigned short f2bf(float f) {
    union { float f; unsigned u; } v; v.f = f;
    unsigned u = v.u;
    return (unsigned short)((u + 0x7fffu + ((u >> 16) & 1u)) >> 16);  // RNE
}
__device__ __forceinline__ unsigned fbits(float f) {
    union { float f; unsigned u; } v; v.f = f; return v.u;
}
// pack two fp32 -> two bf16 (round-half-up): lo16=a, hi16=b
__device__ __forceinline__ unsigned pack_bf2(float a, float b) {
    return __builtin_amdgcn_perm(fbits(b) + 0x8000u, fbits(a) + 0x8000u, 0x07060302u);
}
// single-instruction pack: lo16=bf16(a), hi16=bf16(b), RNE
__device__ __forceinline__ unsigned cvt_pk_bf16(float a, float b) {
    unsigned r;
    asm("v_cvt_pk_bf16_f32 %0, %1, %2" : "=v"(r) : "v"(a), "v"(b));
    return r;
}
// async global->LDS, 16B/lane; LDS dest = wave-uniform base + lane*16
__device__ __forceinline__ void glds16(const void* g, void* l) {
    __builtin_amdgcn_global_load_lds(
        (const __attribute__((address_space(1))) void*)g,
        (__attribute__((address_space(3))) void*)l, 16, 0, 0);
}

// ---------------------------------------------------------------------------
// prep: x->bf16 (blocks [0,6144)), W_qkv transpose ([6144,6576)),
// W_out transpose ([6576,6720)).
// ---------------------------------------------------------------------------
__global__ __launch_bounds__(256)
void prep(const float* __restrict__ x, unsigned short* __restrict__ xb,
          const float* __restrict__ Wq, unsigned short* __restrict__ Wqt,
          const float* __restrict__ Wo, unsigned short* __restrict__ Wot) {
    int b = blockIdx.x;
    if (b < 6144) {
        int i = (b * 256 + threadIdx.x) * 4;
        float4 v = *(const float4*)(x + i);
        uint2 u;
        u.x = pack_bf2(v.x, v.y);
        u.y = pack_bf2(v.z, v.w);
        *(uint2*)(xb + i) = u;
        return;
    }
    __shared__ unsigned short tile[64][65];
    const float* W; unsigned short* Wt; int K, N, bx, by;
    if (b < 6144 + 432) {
        int bb = b - 6144; bx = bb % 36; by = bb / 36;
        W = Wq; Wt = Wqt; K = DMODEL; N = NQKV;
    } else {
        int bb = b - 6576; bx = bb % 12; by = bb / 12;
        W = Wo; Wt = Wot; K = DMODEL; N = DMODEL;
    }
    int k0 = by * 64, n0 = bx * 64;
    int c = threadIdx.x & 63;
    int r0 = threadIdx.x >> 6;
    for (int p = 0; p < 16; ++p) {
        int r = r0 + p * 4;
        tile[r][c] = f2bf(W[(size_t)(k0 + r) * N + n0 + c]);
    }
    __syncthreads();
    for (int p = 0; p < 16; ++p) {
        int n = r0 + p * 4;
        Wt[(size_t)(n0 + n) * K + k0 + c] = tile[c][n];
    }
}

// ---------------------------------------------------------------------------
// QKV GEMM computing C^T: tile rows = qkv-cols (A = Wqkv_t), cols = tokens
// (B = x_bf). Q (incl. bias) pre-scaled by log2(e)/8.
// R16: 192x128 tile, grid 64x12 = 768 blocks = exactly 3/CU, single round.
// Waves 2m x 2n: wave owns 96x64 (acc[6][4]). Staging: wave stages 6 A-
// segments (48 rows) + 4 B-segments (32 rows), running pointers.
// ---------------------------------------------------------------------------
__global__ __launch_bounds__(256, 3)
void gemm_qkv(const unsigned short* __restrict__ Amat, const unsigned short* __restrict__ Bmat,
              const float* __restrict__ bias, unsigned short* __restrict__ qb,
              unsigned short* __restrict__ kb, unsigned short* __restrict__ vtb) {
    __shared__ unsigned short As[192 * 64];     // 24 KB
    __shared__ unsigned short Bs[128 * 64];     // 16 KB
    const int K = DMODEL;
    // XCD remap (grid 64 x 12 = 768 blocks, 768 % 8 == 0): bijective
    int bid = (int)blockIdx.y * 64 + (int)blockIdx.x;
    int idx = bid >> 3;
    int n0 = ((bid & 7) * 8 + (idx & 7)) * 128;         // token tile (0..63)
    int m0 = (idx >> 3) * 192;                          // qkv-col tile (0..11)
    int tid = threadIdx.x, lane = tid & 63, w = tid >> 6;
    int wm = (w >> 1) * 96, wn = (w & 1) * 64;
    int quad = lane >> 4, lc = lane & 15;

    // staging: row = seg*8 + (lane>>3); col chunk gc = (lane&7)^(row&7);
    // row&7 = lane>>3 (seg-invariant) => gc p-invariant; seg stride = 8*K els.
    int gc8 = ((lane & 7) ^ (lane >> 3)) * 8;
    int arow0 = w * 48 + (lane >> 3);
    int brow0 = w * 32 + (lane >> 3);
    const unsigned short* agp0 = Amat + (size_t)(m0 + arow0) * K + gc8;
    const unsigned short* bgp0 = Bmat + (size_t)(n0 + brow0) * K + gc8;
    unsigned short* alp0 = &As[w * 6 * 512];
    unsigned short* blp0 = &Bs[w * 4 * 512];

    int foff[2];
    for (int h = 0; h < 2; ++h)
        foff[h] = lc * 64 + (((quad + 4 * h) ^ (lc & 7)) * 8);

    f32x4 acc[6][4];
    for (int a = 0; a < 6; ++a)
        for (int b2 = 0; b2 < 4; ++b2) acc[a][b2] = (f32x4){0.f, 0.f, 0.f, 0.f};

    for (int k0 = 0; k0 < K; k0 += 64) {
        {
            const unsigned short* ag = agp0;
            for (int p = 0; p < 6; ++p) {
                glds16(ag, alp0 + p * 512);
                ag += 8 * DMODEL;
            }
            const unsigned short* bg = bgp0;
            for (int p = 0; p < 4; ++p) {
                glds16(bg, blp0 + p * 512);
                bg += 8 * DMODEL;
            }
            agp0 += 64; bgp0 += 64;            // running pointers, +128B
        }
        __syncthreads();
        bf16x8 bfr[4][2];
        for (int nt = 0; nt < 4; ++nt)
            for (int h = 0; h < 2; ++h)
                bfr[nt][h] = *(const bf16x8*)(&Bs[wn * 64 + nt * 1024 + foff[h]]);
        for (int mt = 0; mt < 6; ++mt) {
            bf16x8 af0 = *(const bf16x8*)(&As[wm * 64 + mt * 1024 + foff[0]]);
            bf16x8 af1 = *(const bf16x8*)(&As[wm * 64 + mt * 1024 + foff[1]]);
            for (int nt = 0; nt < 4; ++nt) {
                acc[mt][nt] = __builtin_amdgcn_mfma_f32_16x16x32_bf16(
                    af0, bfr[nt][0], acc[mt][nt], 0, 0, 0);
                acc[mt][nt] = __builtin_amdgcn_mfma_f32_16x16x32_bf16(
                    af1, bfr[nt][1], acc[mt][nt], 0, 0, 0);
            }
        }
        __syncthreads();
    }
    const float c2q = 0.18033688f;            // log2(e)/8 folded into Q
    for (int mt = 0; mt < 6; ++mt) {
        int colv = m0 + wm + mt * 16 + quad * 4;      // 4 consecutive qkv-cols
        float4 bv = *(const float4*)(bias + colv);
        int h = colv / 192;
        int r = colv - h * 192;
        int which = r >> 6;                            // uniform over i (64-aligned)
        int d0 = r & 63;
        for (int nt = 0; nt < 4; ++nt) {
            int tok = n0 + wn + nt * 16 + lc;
            int b = tok >> 12, t = tok & 4095;
            size_t bh = (size_t)(b * NH + h);
            float v0 = acc[mt][nt][0] + bv.x, v1 = acc[mt][nt][1] + bv.y;
            float v2 = acc[mt][nt][2] + bv.z, v3 = acc[mt][nt][3] + bv.w;
            if (which == 0) {
                uint2 u;
                u.x = cvt_pk_bf16(v0 * c2q, v1 * c2q);
                u.y = cvt_pk_bf16(v2 * c2q, v3 * c2q);
                *(uint2*)(qb + (bh * TT + t) * DK + d0) = u;
            } else if (which == 1) {
                uint2 u;
                u.x = cvt_pk_bf16(v0, v1);
                u.y = cvt_pk_bf16(v2, v3);
                *(uint2*)(kb + (bh * TT + t) * DK + d0) = u;
            } else {
                unsigned short* vp = vtb + (bh * DK + d0) * TT + t;
                vp[0] = f2bf(v0); vp[TT] = f2bf(v1);
                vp[2 * TT] = f2bf(v2); vp[3 * TT] = f2bf(v3);
            }
        }
    }
}

// ---------------------------------------------------------------------------
// Flash attention tile body (R7 form). DIAG selects causal masking (wave-
// uniform branch at call site). PV interleaved per ktile. Row-sum l via
// ones x P MFMA (5th accumulator). T5 setprio; cvt_pk P-pack (1 inst/2 f32).
// ---------------------------------------------------------------------------
template <bool DIAG>
__device__ __forceinline__ void flash_tile(const unsigned short* __restrict__ Kb,
                                           const unsigned short* __restrict__ Vb,
                                           bf16x8 qf0, bf16x8 qf1,
                                           f32x4 (&o)[4], f32x4& ol,
                                           int kt, int q_lo, int quad, int lc) {
    int c0 = quad ^ (lc & 7);
    int sw = lc & 7;
    const bf16x4 ones = {(short)0x3F80, (short)0x3F80, (short)0x3F80, (short)0x3F80};
    for (int ktile = 0; ktile < 4; ++ktile) {
        bf16x8 kf0 = *(const bf16x8*)(&Kb[(ktile * 16 + lc) * 64 + c0 * 8]);
        bf16x8 kf1 = *(const bf16x8*)(&Kb[(ktile * 16 + lc) * 64 + (c0 ^ 4) * 8]);
        f32x4 s = (f32x4){0.f, 0.f, 0.f, 0.f};
        __builtin_amdgcn_s_setprio(1);
        s = __builtin_amdgcn_mfma_f32_16x16x32_bf16(kf0, qf0, s, 0, 0, 0);
        s = __builtin_amdgcn_mfma_f32_16x16x32_bf16(kf1, qf1, s, 0, 0, 0);
        __builtin_amdgcn_s_setprio(0);
        float p[4];
        if (DIAG) {
            int key0 = kt + ktile * 16 + quad * 4;
            int qcol = q_lo + lc;
            for (int i = 0; i < 4; ++i) {
                float e = __builtin_amdgcn_exp2f(s[i]);
                if (key0 + i > qcol) e = 0.f;
                p[i] = e;
            }
        } else {
            for (int i = 0; i < 4; ++i) p[i] = __builtin_amdgcn_exp2f(s[i]);
        }
        union { uint2 u; bf16x4 v; } pc;
        pc.u.x = cvt_pk_bf16(p[0], p[1]);
        pc.u.y = cvt_pk_bf16(p[2], p[3]);
        int c8 = (ktile * 2 + (quad >> 1)) ^ sw;
        int voff = c8 * 8 + (quad & 1) * 4;
        __builtin_amdgcn_s_setprio(1);
        ol = __builtin_amdgcn_mfma_f32_16x16x16bf16_1k(ones, pc.v, ol, 0, 0, 0);
        for (int dt = 0; dt < 4; ++dt) {
            bf16x4 vf = *(const bf16x4*)(&Vb[(dt * 16 + lc) * 64 + voff]);
            o[dt] = __builtin_amdgcn_mfma_f32_16x16x16bf16_1k(vf, pc.v, o[dt], 0, 0, 0);
        }
        __builtin_amdgcn_s_setprio(0);
    }
}

// ---------------------------------------------------------------------------
// Flash attention (causal), R7 form + running staging pointers. 256 thr =
// 4 waves x 16 q rows (64-row q tile); heavy-first; K/V glds double-buffer;
// P in registers; fixed-max softmax. Waves 0-1 stage K, waves 2-3 stage V.
// ---------------------------------------------------------------------------
__global__ __launch_bounds__(256)
void flash_attn(const unsigned short* __restrict__ qbuf,
                const unsigned short* __restrict__ kbuf,
                const unsigned short* __restrict__ vtbuf,
                unsigned short* __restrict__ ctx) {
    __shared__ unsigned short Ks[2][64 * 64];      // [key][d], swizzled
    __shared__ unsigned short Vs[2][64 * 64];      // [d][key], swizzled
    int bh = blockIdx.x;
    int qblk = 63 - (int)blockIdx.y;               // heavy blocks dispatch first
    int tid = threadIdx.x, lane = tid & 63, w = tid >> 6;
    int quad = lane >> 4, lc = lane & 15;
    const size_t base = (size_t)bh * TT * DK;
    int col8 = ((lane & 7) ^ (lane >> 3)) * 8;     // glds swizzled source col
    size_t hb = (size_t)(bh / NH) * TT * DMODEL + (size_t)(bh % NH) * DK;

    int q_lo = qblk * 64 + w * 16;                 // this wave's 16 q rows
    int ntile = qblk + 1;

    // running staging pointers: waves 0-1 stage K rows, waves 2-3 stage V rows
    int rb = (w & 1) * 4;
    const unsigned short* sgp[4];
    int stepEls;
    if (w < 2) {
        const unsigned short* kb0 = kbuf + base + (size_t)(lane >> 3) * DK + col8;
        for (int r = 0; r < 4; ++r) sgp[r] = kb0 + (size_t)((rb + r) * 8) * DK;
        stepEls = 64 * DK;                         // next 64-key tile: +8192B
    } else {
        const unsigned short* vb0 = vtbuf + base + (size_t)(lane >> 3) * TT + col8;
        for (int r = 0; r < 4; ++r) sgp[r] = vb0 + (size_t)((rb + r) * 8) * TT;
        stepEls = 64;                              // next 64-key cols: +128B
    }

    bf16x8 qf0, qf1;                               // pre-scaled Q fragment
    {
        const unsigned short* qp = qbuf + base + (size_t)(q_lo + lc) * DK;
        qf0 = *(const bf16x8*)(qp + quad * 8);
        qf1 = *(const bf16x8*)(qp + 32 + quad * 8);
    }
    f32x4 o[4];
    for (int dt = 0; dt < 4; ++dt) o[dt] = (f32x4){0.f, 0.f, 0.f, 0.f};
    f32x4 ol = (f32x4){0.f, 0.f, 0.f, 0.f};       // row-sum accumulator

    {   // stage tile 0 -> buf 0
        if (w < 2)
            for (int r = 0; r < 4; ++r) {
                glds16(sgp[r], &Ks[0][(rb + r) * 512]);
                sgp[r] += stepEls;
            }
        else
            for (int r = 0; r < 4; ++r) {
                glds16(sgp[r], &Vs[0][(rb + r) * 512]);
                sgp[r] += stepEls;
            }
    }
    __syncthreads();

    for (int ti = 0; ti < ntile; ++ti) {
        int cur = ti & 1;
        if (ti + 1 < ntile) {                      // async prefetch -> alt buf
            if (w < 2)
                for (int r = 0; r < 4; ++r) {
                    glds16(sgp[r], &Ks[cur ^ 1][(rb + r) * 512]);
                    sgp[r] += stepEls;
                }
            else
                for (int r = 0; r < 4; ++r) {
                    glds16(sgp[r], &Vs[cur ^ 1][(rb + r) * 512]);
                    sgp[r] += stepEls;
                }
        }
        int kt = ti * 64;
        if (ti == ntile - 1)
            flash_tile<true>(&Ks[cur][0], &Vs[cur][0], qf0, qf1, o, ol,
                             kt, q_lo, quad, lc);
        else
            flash_tile<false>(&Ks[cur][0], &Vs[cur][0], qf0, qf1, o, ol,
                              kt, q_lo, quad, lc);
        __syncthreads();                           // cur consumed; alt staged
    }

    // epilogue: l_q already complete per lane (ones-MFMA); normalize, store
    float inv = 1.f / ol[0];
    int t = q_lo + lc;
    unsigned short* cp = ctx + hb + (size_t)t * DMODEL;
    for (int dt = 0; dt < 4; ++dt) {
        uint2 u;
        u.x = cvt_pk_bf16(o[dt][0] * inv, o[dt][1] * inv);
        u.y = cvt_pk_bf16(o[dt][2] * inv, o[dt][3] * inv);
        *(uint2*)(cp + dt * 16 + quad * 4) = u;
    }
}

// ---------------------------------------------------------------------------
// Out GEMM computing C^T, 64 out-cols x 128 tokens per block (768 blocks).
// A = Wout_t (64 rows), B = ctx (128 rows); unified LDS, glds staging with
// running pointers. launch_bounds(256,4): 4 blocks/CU. XCD-rectangle remap.
// ---------------------------------------------------------------------------
__global__ __launch_bounds__(256, 4)
void gemm_out(const unsigned short* __restrict__ Amat, const unsigned short* __restrict__ Bmat,
              const float* __restrict__ bias, float* __restrict__ out) {
    __shared__ unsigned short S[(64 + 128) * 64];   // A then B, 24 KB
    const int K = DMODEL;
    // XCD-rectangle remap (grid 64 x 12 = 768 blocks, 768 % 8 == 0)
    int bid = (int)blockIdx.y * 64 + (int)blockIdx.x;
    int idx = bid >> 3;
    int n0 = ((bid & 7) * 8 + (idx & 7)) * 128;        // token tile
    int m0 = (idx >> 3) * 64;                          // out-col tile
    int tid = threadIdx.x, lane = tid & 63, w = tid >> 6;
    int wm = (w & 1) * 32, wn = (w >> 1) * 64;
    int quad = lane >> 4, lc = lane & 15;

    const unsigned short* gp[6]; unsigned short* lp[6];
    for (int p = 0; p < 6; ++p) {
        int c = (w * 6 + p) * 64 + lane;      // 16B chunk id (A:0..511, B:512..1535)
        if (c < 512) {
            int row = c >> 3, gc = (c & 7) ^ (row & 7);
            gp[p] = Amat + (size_t)(m0 + row) * K + gc * 8;
        } else {
            int cb = c - 512;
            int row = cb >> 3, gc = (cb & 7) ^ (row & 7);
            gp[p] = Bmat + (size_t)(n0 + row) * K + gc * 8;
        }
        lp[p] = &S[(w * 6 + p) * 512];
    }
    int foffA[2][2], foffB[4][2];
    for (int mt = 0; mt < 2; ++mt)
        for (int h = 0; h < 2; ++h)
            foffA[mt][h] = (wm + mt * 16 + lc) * 64 + (((quad + 4 * h) ^ (lc & 7)) * 8);
    for (int nt = 0; nt < 4; ++nt)
        for (int h = 0; h < 2; ++h)
            foffB[nt][h] = 4096 + (wn + nt * 16 + lc) * 64 + (((quad + 4 * h) ^ (lc & 7)) * 8);

    f32x4 acc[2][4];
    for (int a = 0; a < 2; ++a)
        for (int b2 = 0; b2 < 4; ++b2) acc[a][b2] = (f32x4){0.f, 0.f, 0.f, 0.f};

    for (int k0 = 0; k0 < K; k0 += 64) {
        for (int p = 0; p < 6; ++p) {
            glds16(gp[p], lp[p]);
            gp[p] += 64;                       // running pointers, +128B
        }
        __syncthreads();
        bf16x8 af[2][2], bfr[4][2];
        for (int mt = 0; mt < 2; ++mt)
            for (int h = 0; h < 2; ++h) af[mt][h] = *(const bf16x8*)(&S[foffA[mt][h]]);
        for (int nt = 0; nt < 4; ++nt)
            for (int h = 0; h < 2; ++h) bfr[nt][h] = *(const bf16x8*)(&S[foffB[nt][h]]);
        for (int mt = 0; mt < 2; ++mt)
            for (int nt = 0; nt < 4; ++nt) {
                acc[mt][nt] = __builtin_amdgcn_mfma_f32_16x16x32_bf16(
                    af[mt][0], bfr[nt][0], acc[mt][nt], 0, 0, 0);
                acc[mt][nt] = __builtin_amdgcn_mfma_f32_16x16x32_bf16(
                    af[mt][1], bfr[nt][1], acc[mt][nt], 0, 0, 0);
            }
        __syncthreads();
    }
    for (int mt = 0; mt < 2; ++mt) {
        int colv = m0 + wm + mt * 16 + quad * 4;
        float4 bv = *(const float4*)(bias + colv);
        for (int nt = 0; nt < 4; ++nt) {
            int tok = n0 + wn + nt * 16 + lc;
            float4 ov;
            ov.x = acc[mt][nt][0] + bv.x;
            ov.y = acc[mt][nt][1] + bv.y;
            ov.z = acc[mt][nt][2] + bv.z;
            ov.w = acc[mt][nt][3] + bv.w;
            *(float4*)(out + (size_t)tok * DMODEL + colv) = ov;
        }
    }
}

// ---------------------------------------------------------------------------
extern "C" void kernel_launch(void* const* d_in, const int* in_sizes, int n_in,
                              void* d_out, int out_size, void* d_ws, size_t ws_size,
                              hipStream_t stream) {
    const float* x     = (const float*)d_in[0];
    // d_in[1] = mask (hard-coded causal; unused)
    const float* W_qkv = (const float*)d_in[2];
    const float* b_qkv = (const float*)d_in[3];
    const float* W_out = (const float*)d_in[4];
    const float* b_out = (const float*)d_in[5];
    float* out = (float*)d_out;

    unsigned short* ws = (unsigned short*)d_ws;
    unsigned short* Wqkv_t = ws;                                    // 2304*768
    unsigned short* Wout_t = Wqkv_t + (size_t)NQKV * DMODEL;        // 768*768
    unsigned short* q_buf  = Wout_t + (size_t)DMODEL * DMODEL;      // 24*4096*64
    unsigned short* k_buf  = q_buf  + (size_t)2 * NH * TT * DK;
    unsigned short* vt_buf = k_buf  + (size_t)2 * NH * TT * DK;
    unsigned short* ctx    = vt_buf + (size_t)2 * NH * TT * DK;     // 2*4096*768
    unsigned short* x_bf   = ctx;   // alias: dead before flash writes ctx

    prep<<<dim3(6720), 256, 0, stream>>>(x, x_bf, W_qkv, Wqkv_t, W_out, Wout_t);
    gemm_qkv<<<dim3((2 * TT) / 128, NQKV / 192), 256, 0, stream>>>(
        Wqkv_t, x_bf, b_qkv, q_buf, k_buf, vt_buf);
    flash_attn<<<dim3(2 * NH, TT / 64), 256, 0, stream>>>(q_buf, k_buf, vt_buf, ctx);
    gemm_out<<<dim3((2 * TT) / 128, DMODEL / 64), 256, 0, stream>>>(
        Wout_t, ctx, b_out, out);
}